// Round 6
// baseline (17408.049 us; speedup 1.0000x reference)
//
#include <hip/hip_runtime.h>

#define TT 1024
#define BB 64
#define DD 512
#define HH 512
#define NG 4       // batch groups (16 batches each)
#define BPG 16
#define NSL 16     // hidden slices (32 units each)
#define NTHR 256

typedef short s8v __attribute__((ext_vector_type(8)));
typedef float f4v __attribute__((ext_vector_type(4)));
typedef int i4v __attribute__((ext_vector_type(4)));

static __device__ __forceinline__ unsigned short f2bf(float f) {
  union { float f; unsigned int u; } v; v.f = f;
  unsigned int r = v.u + 0x7FFFu + ((v.u >> 16) & 1u);  // RNE
  return (unsigned short)(r >> 16);
}
static __device__ __forceinline__ i4v ld_b128_cohere(const void* p) {
  i4v r;
  asm volatile("global_load_dwordx4 %0, %1, off sc0 sc1"
               : "=v"(r) : "v"(p) : "memory");
  return r;
}
static __device__ __forceinline__ void st_b64_cohere(void* p,
                                                     unsigned long long v) {
  asm volatile("global_store_dwordx2 %0, %1, off sc0 sc1"
               :: "v"(p), "v"(v) : "memory");
}
static __device__ __forceinline__ unsigned int cvtpk_bf16(float lo, float hi) {
  unsigned int r;
  asm("v_cvt_pk_bf16_f32 %0, %1, %2" : "=v"(r) : "v"(lo), "v"(hi));
  return r;
}

// Wipe h tags every launch: first (correctness) call sees no garbage tags,
// and each graph replay re-poisons so polls are real (no stale-tag fastpath).
__global__ void __launch_bounds__(256, 1) qlstm_init(
    unsigned long long* hbuf64) {
  hbuf64[blockIdx.x * 256 + threadIdx.x] = 0xFFFFFFFF00000000ull;
}

// One-time X fp32 -> bf16 (row-major preserved).
__global__ void __launch_bounds__(256, 1) qlstm_cvt(
    const float* __restrict__ X, unsigned short* __restrict__ xb) {
  const size_t np = (size_t)TT * BB * DD / 8;
  for (size_t p = (size_t)blockIdx.x * 256 + threadIdx.x; p < np;
       p += (size_t)gridDim.x * 256) {
    const float4 a = ((const float4*)X)[2 * p];
    const float4 b = ((const float4*)X)[2 * p + 1];
    i4v w;
    w[0] = cvtpk_bf16(a.x, a.y);
    w[1] = cvtpk_bf16(a.z, a.w);
    w[2] = cvtpk_bf16(b.x, b.y);
    w[3] = cvtpk_bf16(b.z, b.w);
    ((i4v*)xb)[p] = w;
  }
}

// XBF=1: X prefetched as bf16 from ws. XBF=0: fallback, fp32 X + in-loop cvt.
template <int XBF>
__global__ void __launch_bounds__(NTHR, 1) qlstm_main(
    const float* __restrict__ X, const unsigned short* __restrict__ xb,
    const float* __restrict__ Wf, const float* __restrict__ bfp,
    const float* __restrict__ Wi, const float* __restrict__ bip,
    const float* __restrict__ Wg, const float* __restrict__ bgp,
    const float* __restrict__ Wo, const float* __restrict__ bop,
    const float* __restrict__ phase,
    float* __restrict__ out, unsigned long long* __restrict__ hbuf64) {
  const int tid   = threadIdx.x;
  const int wv    = tid >> 6;
  const int lane  = tid & 63;
  const int n     = lane & 15;
  const int kg    = lane >> 4;
  const int group = blockIdx.x & (NG - 1);
  const int slice = blockIdx.x / NG;
  const int b0 = group * BPG;
  const int us = slice * 32 + wv * 8;   // this wave's 8 units

  // Packed B-frag weights (per wave): tile0 = {f(n<8)|i(n>=8)}, tile1 = {g|o},
  // unit = us + (n&7). x-part rows 0..511, h-part rows 512..1023.
  const float* Wt0 = (n < 8) ? Wf : Wi;
  const float* Wt1 = (n < 8) ? Wg : Wo;
  const int wcol = us + (n & 7);
  s8v wx0[16], wx1[16], wh0[16], wh1[16];
#pragma unroll
  for (int kc = 0; kc < 16; ++kc) {
#pragma unroll
    for (int j = 0; j < 8; ++j) {
      const int rx = kc * 32 + kg * 8 + j;
      wx0[kc][j] = (short)f2bf(Wt0[(size_t)rx * HH + wcol]);
      wx1[kc][j] = (short)f2bf(Wt1[(size_t)rx * HH + wcol]);
      wh0[kc][j] = (short)f2bf(Wt0[(size_t)(512 + rx) * HH + wcol]);
      wh1[kc][j] = (short)f2bf(Wt1[(size_t)(512 + rx) * HH + wcol]);
    }
  }
  const int uu = us + (n & 7);
  const float bz0 = bfp[uu] + phase[uu];
  const float bz1 = bip[uu] + phase[uu];
  const float bz2 = bgp[uu] + phase[uu];
  const float bz3 = bop[uu] + phase[uu];
  float cst[4] = {0.f, 0.f, 0.f, 0.f};

  // x(0) prefetch (bf16 path): lane(n,kg) A-frag rows = batch b0+n.
  s8v xf[16];
  if (XBF) {
    const unsigned short* xr = xb + ((size_t)0 * BB + b0 + n) * DD + kg * 8;
#pragma unroll
    for (int kc = 0; kc < 16; ++kc) xf[kc] = *(const s8v*)(xr + kc * 32);
  }

  for (int t = 0; t < TT; ++t) {
    // ---- [1] x-part MFMAs (independent of h) ----
    f4v ax0 = {0.f, 0.f, 0.f, 0.f}, ax1 = {0.f, 0.f, 0.f, 0.f};
    if (XBF) {
#pragma unroll
      for (int kc = 0; kc < 16; ++kc) {
        ax0 = __builtin_amdgcn_mfma_f32_16x16x32_bf16(xf[kc], wx0[kc], ax0, 0, 0, 0);
        ax1 = __builtin_amdgcn_mfma_f32_16x16x32_bf16(xf[kc], wx1[kc], ax1, 0, 0, 0);
      }
    } else {
      const float* Xr = X + ((size_t)t * BB + b0 + n) * DD + kg * 8;
#pragma unroll
      for (int kc = 0; kc < 16; ++kc) {
        const float4 xa = *(const float4*)(Xr + kc * 32);
        const float4 xc = *(const float4*)(Xr + kc * 32 + 4);
        union { s8v s; unsigned int d[4]; } af;
        af.d[0] = cvtpk_bf16(xa.x, xa.y);
        af.d[1] = cvtpk_bf16(xa.z, xa.w);
        af.d[2] = cvtpk_bf16(xc.x, xc.y);
        af.d[3] = cvtpk_bf16(xc.z, xc.w);
        ax0 = __builtin_amdgcn_mfma_f32_16x16x32_bf16(af.s, wx0[kc], ax0, 0, 0, 0);
        ax1 = __builtin_amdgcn_mfma_f32_16x16x32_bf16(af.s, wx1[kc], ax1, 0, 0, 0);
      }
    }

    // ---- [2] poll DIRECTLY on tagged h(t-1); [3] h-MFMAs ----
    f4v ah0 = {0.f, 0.f, 0.f, 0.f}, ah1 = {0.f, 0.f, 0.f, 0.f};
    if (t > 0) {
      const int tm1 = t - 1;
      const unsigned long long* hb = hbuf64 + (size_t)(tm1 & 1) * BB * 256 +
                                     (size_t)(b0 + n) * 256 + kg * 4;
      i4v hf[32];
      for (;;) {
#pragma unroll
        for (int kc = 0; kc < 16; ++kc) {
          hf[2 * kc]     = ld_b128_cohere(hb + kc * 16);
          hf[2 * kc + 1] = ld_b128_cohere(hb + kc * 16 + 2);
        }
        asm volatile("s_waitcnt vmcnt(0)" ::: "memory");
        __builtin_amdgcn_sched_barrier(0);
        int bad = 0;
#pragma unroll
        for (int j = 0; j < 32; ++j)
          bad |= (hf[j][1] ^ tm1) | (hf[j][3] ^ tm1);
        if (__all(bad == 0)) break;
        __builtin_amdgcn_s_sleep(1);
      }
#pragma unroll
      for (int kc = 0; kc < 16; ++kc) {
        union { i4v i; s8v s; } af;
        af.i[0] = hf[2 * kc][0];
        af.i[1] = hf[2 * kc][2];
        af.i[2] = hf[2 * kc + 1][0];
        af.i[3] = hf[2 * kc + 1][2];
        ah0 = __builtin_amdgcn_mfma_f32_16x16x32_bf16(af.s, wh0[kc], ah0, 0, 0, 0);
        ah1 = __builtin_amdgcn_mfma_f32_16x16x32_bf16(af.s, wh1[kc], ah1, 0, 0, 0);
      }
    }

    // ---- [4] issue x(t+1) prefetch (xf regs dead since [1]) ----
    if (XBF && t + 1 < TT) {
      const unsigned short* xr =
          xb + ((size_t)(t + 1) * BB + b0 + n) * DD + kg * 8;
#pragma unroll
      for (int kc = 0; kc < 16; ++kc) xf[kc] = *(const s8v*)(xr + kc * 32);
    }

    // ---- [5] gates (lane pair n <-> n^8 packs {f,i} / {g,o}) ----
    float hv[4];
#pragma unroll
    for (int i = 0; i < 4; ++i) {
      const float s0 = ax0[i] + ah0[i];
      const float s1 = ax1[i] + ah1[i];
      const float p0 = __shfl_xor(s0, 8);
      const float p1 = __shfl_xor(s1, 8);
      const bool lo = (n < 8);
      const float zf = (lo ? s0 : p0) + bz0;
      const float zi = (lo ? p0 : s0) + bz1;
      const float zg = (lo ? s1 : p1) + bz2;
      const float zo = (lo ? p1 : s1) + bz3;
      const float fg = 1.f / (1.f + __expf(-zf));
      const float ig = 1.f / (1.f + __expf(-zi));
      const float gg = 1.f - 2.f / (__expf(2.f * zg) + 1.f);
      const float og = 1.f / (1.f + __expf(-zo));
      cst[i] = fg * cst[i] + ig * gg;
      hv[i] = og * (1.f - 2.f / (__expf(2.f * cst[i]) + 1.f));
    }

    // ---- [6] publish tagged h(t): fire-and-forget (tags = validity) ----
    float hn[4];
#pragma unroll
    for (int i = 0; i < 4; ++i) hn[i] = __shfl_down(hv[i], 1);
    if (n < 8 && !(n & 1)) {
      unsigned long long* hp =
          hbuf64 + (size_t)(t & 1) * BB * 256 + (us + n) / 2;
#pragma unroll
      for (int i = 0; i < 4; ++i) {
        const unsigned long long d =
            ((unsigned long long)(unsigned)t << 32) |
            (unsigned long long)cvtpk_bf16(hv[i], hn[i]);
        st_b64_cohere(hp + (size_t)(b0 + 4 * kg + i) * 256, d);
      }
    }

    // ---- [7] out stores (off critical path) ----
    if (n < 8) {
#pragma unroll
      for (int i = 0; i < 4; ++i)
        out[(size_t)t * BB * HH + (size_t)(b0 + 4 * kg + i) * HH + uu] = hv[i];
      if (t == TT - 1) {
#pragma unroll
        for (int i = 0; i < 4; ++i) {
          out[(size_t)TT * BB * HH + (size_t)(b0 + 4 * kg + i) * HH + uu] = hv[i];
          out[(size_t)TT * BB * HH + BB * HH +
              (size_t)(b0 + 4 * kg + i) * HH + uu] = cst[i];
        }
      }
    }
  }
}

extern "C" void kernel_launch(void* const* d_in, const int* in_sizes, int n_in,
                              void* d_out, int out_size, void* d_ws,
                              size_t ws_size, hipStream_t stream) {
  const float* X   = (const float*)d_in[0];
  const float* Wf  = (const float*)d_in[1];
  const float* bfp = (const float*)d_in[2];
  const float* Wi  = (const float*)d_in[3];
  const float* bip = (const float*)d_in[4];
  const float* Wg  = (const float*)d_in[5];
  const float* bgp = (const float*)d_in[6];
  const float* Wo  = (const float*)d_in[7];
  const float* bop = (const float*)d_in[8];
  const float* ph  = (const float*)d_in[9];
  float* out = (float*)d_out;

  // ws: [0, 256KB) tagged-h double buffer {bf16 pair | u32 tag} u64 words
  //     [1MB, 1MB+64MB) X as bf16 (if ws_size permits)
  unsigned long long* hbuf64 = (unsigned long long*)d_ws;
  unsigned short* xb = (unsigned short*)((char*)d_ws + (1u << 20));
  const size_t need = (1u << 20) + (size_t)TT * BB * DD * 2 + 1024;

  qlstm_init<<<128, 256, 0, stream>>>(hbuf64);
  if (ws_size >= need) {
    qlstm_cvt<<<2048, 256, 0, stream>>>(X, xb);
    qlstm_main<1><<<NG * NSL, NTHR, 0, stream>>>(X, xb, Wf, bfp, Wi, bip, Wg,
                                                 bgp, Wo, bop, ph, out, hbuf64);
  } else {
    qlstm_main<0><<<NG * NSL, NTHR, 0, stream>>>(X, xb, Wf, bfp, Wi, bip, Wg,
                                                 bgp, Wo, bop, ph, out, hbuf64);
  }
}

// Round 7
// 8440.469 us; speedup vs baseline: 2.0625x; 2.0625x over previous
//
#include <hip/hip_runtime.h>

#define TT 1024
#define BB 64
#define DD 512
#define HH 512
#define NG 4       // batch groups (16 batches each)
#define BPG 16
#define NS 32      // hidden slices (16 units each)
#define UPS 16
#define NTHR 256

typedef short s8v __attribute__((ext_vector_type(8)));
typedef float f4v __attribute__((ext_vector_type(4)));
typedef int i4v __attribute__((ext_vector_type(4)));

static __device__ __forceinline__ unsigned short f2bf(float f) {
  union { float f; unsigned int u; } v; v.f = f;
  unsigned int r = v.u + 0x7FFFu + ((v.u >> 16) & 1u);  // RNE
  return (unsigned short)(r >> 16);
}
static __device__ __forceinline__ i4v ld_b128_cohere(const void* p) {
  i4v r;
  asm volatile("global_load_dwordx4 %0, %1, off sc0 sc1"
               : "=v"(r) : "v"(p) : "memory");
  return r;
}
static __device__ __forceinline__ void st_b64_cohere(void* p,
                                                     unsigned long long v) {
  asm volatile("global_store_dwordx2 %0, %1, off sc0 sc1"
               :: "v"(p), "v"(v) : "memory");
}
static __device__ __forceinline__ unsigned int cvtpk_bf16(float lo, float hi) {
  unsigned int r;
  asm("v_cvt_pk_bf16_f32 %0, %1, %2" : "=v"(r) : "v"(lo), "v"(hi));
  return r;
}

// Wipe h tags every launch (graph replays rerun this): no stale-tag fastpath,
// no garbage-tag match. 2*64*256 u64 = 32768 words.
__global__ void __launch_bounds__(256, 1) qlstm_init(
    unsigned long long* hbuf64) {
  hbuf64[blockIdx.x * 256 + threadIdx.x] = 0xFFFFFFFF00000000ull;
}

__global__ void __launch_bounds__(NTHR, 1) qlstm_main(
    const float* __restrict__ X,
    const float* __restrict__ Wf, const float* __restrict__ bfp,
    const float* __restrict__ Wi, const float* __restrict__ bip,
    const float* __restrict__ Wg, const float* __restrict__ bgp,
    const float* __restrict__ Wo, const float* __restrict__ bop,
    const float* __restrict__ phase,
    float* __restrict__ out, unsigned long long* __restrict__ hbuf64) {
  // 4-deep zx ring + progress counters. zbuf write/read: 16B/lane stride-1 ->
  // conflict-free. No other LDS, no __syncthreads in steady state.
  __shared__ float zbuf[4][2][2][64][4];  // [slot][uh][tile][lane][i]
  __shared__ int xcnt[2], hcnt[2];
  const int tid   = threadIdx.x;
  const int wv    = tid >> 6;
  const int lane  = tid & 63;
  const int n     = lane & 15;
  const int kg    = lane >> 4;
  const int group = blockIdx.x & (NG - 1);
  const int slice = blockIdx.x / NG;
  const int b0 = group * BPG;
  const int u0 = slice * UPS;
  const bool isH = (wv >= 2);
  const int uh = wv & 1;               // unit half (8 units each)
  const int us = u0 + uh * 8;

  // Packed B-frag tiles: tile0 = {f(n<8)|i(n>=8)}, tile1 = {g|o}, unit us+(n&7).
  const float* Wt0 = (n < 8) ? Wf : Wi;
  const float* Wt1 = (n < 8) ? Wg : Wo;
  const int wcol = us + (n & 7);

  if (tid < 2) { xcnt[tid] = 0; hcnt[tid] = 0; }
  __syncthreads();   // the only barrier

  if (!isH) {
    // ========== x-waves: free-running zx producer (<=4 steps ahead) ==========
    s8v wx0[16], wx1[16];            // x-part weights (K rows 0..511)
#pragma unroll
    for (int kc = 0; kc < 16; ++kc)
#pragma unroll
      for (int j = 0; j < 8; ++j) {
        const int rx = kc * 32 + kg * 8 + j;
        wx0[kc][j] = (short)f2bf(Wt0[(size_t)rx * HH + wcol]);
        wx1[kc][j] = (short)f2bf(Wt1[(size_t)rx * HH + wcol]);
      }
    float4 xv[16];
    s8v xf[16];
    {  // preload x(0) frags
      const float4* Xr = (const float4*)(X + ((size_t)0 * BB + b0 + n) * DD) + kg * 2;
#pragma unroll
      for (int kc = 0; kc < 16; ++kc) {
        xv[kc] = Xr[kc * 8];
        const float4 x2 = Xr[kc * 8 + 1];
        xf[kc][0] = (short)(cvtpk_bf16(xv[kc].x, xv[kc].y) & 0xFFFF);
        // (build via unions below instead — keep simple here)
        union { s8v s; unsigned int d[4]; } af;
        af.d[0] = cvtpk_bf16(xv[kc].x, xv[kc].y);
        af.d[1] = cvtpk_bf16(xv[kc].z, xv[kc].w);
        af.d[2] = cvtpk_bf16(x2.x, x2.y);
        af.d[3] = cvtpk_bf16(x2.z, x2.w);
        xf[kc] = af.s;
      }
    }
    int hcv = 0;
    for (int tx = 0; tx < TT; ++tx) {
      // issue next-step X loads early (consumed after MFMA+handoff)
      float4 yv[16];
      const bool pf = (tx + 1 < TT);
      if (pf) {
        const float4* Xr =
            (const float4*)(X + ((size_t)(tx + 1) * BB + b0 + n) * DD) + kg * 2;
#pragma unroll
        for (int kc = 0; kc < 16; ++kc) { yv[kc] = Xr[kc * 8]; xv[kc] = Xr[kc * 8 + 1]; }
      }
      // ring throttle: slot tx&3 free once h consumed step tx-4
      while (tx >= hcv + 4) {
        const int h0 = __hip_atomic_load(&hcnt[0], __ATOMIC_ACQUIRE,
                                         __HIP_MEMORY_SCOPE_WORKGROUP);
        const int h1 = __hip_atomic_load(&hcnt[1], __ATOMIC_ACQUIRE,
                                         __HIP_MEMORY_SCOPE_WORKGROUP);
        hcv = (h0 < h1) ? h0 : h1;
        if (tx >= hcv + 4) __builtin_amdgcn_s_sleep(1);
      }
      f4v a0 = {0.f, 0.f, 0.f, 0.f}, a1 = {0.f, 0.f, 0.f, 0.f};
#pragma unroll
      for (int kc = 0; kc < 16; ++kc) {
        a0 = __builtin_amdgcn_mfma_f32_16x16x32_bf16(xf[kc], wx0[kc], a0, 0, 0, 0);
        a1 = __builtin_amdgcn_mfma_f32_16x16x32_bf16(xf[kc], wx1[kc], a1, 0, 0, 0);
      }
      *(f4v*)&zbuf[tx & 3][uh][0][lane][0] = a0;
      *(f4v*)&zbuf[tx & 3][uh][1][lane][0] = a1;
      asm volatile("s_waitcnt lgkmcnt(0)" ::: "memory");
      __hip_atomic_store(&xcnt[uh], tx + 1, __ATOMIC_RELEASE,
                         __HIP_MEMORY_SCOPE_WORKGROUP);
      if (pf) {   // convert prefetched X -> frags (compiler waits on vmcnt)
#pragma unroll
        for (int kc = 0; kc < 16; ++kc) {
          union { s8v s; unsigned int d[4]; } af;
          af.d[0] = cvtpk_bf16(yv[kc].x, yv[kc].y);
          af.d[1] = cvtpk_bf16(yv[kc].z, yv[kc].w);
          af.d[2] = cvtpk_bf16(xv[kc].x, xv[kc].y);
          af.d[3] = cvtpk_bf16(xv[kc].z, xv[kc].w);
          xf[kc] = af.s;
        }
      }
    }
  } else {
    // ================= h-waves: the critical path =================
    s8v wh0[16], wh1[16];            // h-part weights (K rows 512..1023)
#pragma unroll
    for (int kc = 0; kc < 16; ++kc)
#pragma unroll
      for (int j = 0; j < 8; ++j) {
        const int rh = 512 + kc * 32 + kg * 8 + j;
        wh0[kc][j] = (short)f2bf(Wt0[(size_t)rh * HH + wcol]);
        wh1[kc][j] = (short)f2bf(Wt1[(size_t)rh * HH + wcol]);
      }
    const int uu = us + (n & 7);
    const float bz0 = bfp[uu] + phase[uu];
    const float bz1 = bip[uu] + phase[uu];
    const float bz2 = bgp[uu] + phase[uu];
    const float bz3 = bop[uu] + phase[uu];
    float cst[4] = {0.f, 0.f, 0.f, 0.f};
    int xcv = 0;

    for (int t = 0; t < TT; ++t) {
      // ---- [1] tag-poll h(t-1): data + validity in one L3 round trip ----
      f4v ah0 = {0.f, 0.f, 0.f, 0.f}, ah1 = {0.f, 0.f, 0.f, 0.f};
      if (t > 0) {
        const int tm1 = t - 1;
        const unsigned long long* hb = hbuf64 + (size_t)(tm1 & 1) * BB * 256 +
                                       (size_t)(b0 + n) * 256 + kg * 4;
        i4v hf[32];
        for (;;) {
#pragma unroll
          for (int kc = 0; kc < 16; ++kc) {
            hf[2 * kc]     = ld_b128_cohere(hb + kc * 16);
            hf[2 * kc + 1] = ld_b128_cohere(hb + kc * 16 + 2);
          }
          asm volatile("s_waitcnt vmcnt(0)" ::: "memory");
          __builtin_amdgcn_sched_barrier(0);
          int bad = 0;
#pragma unroll
          for (int j = 0; j < 32; ++j)
            bad |= (hf[j][1] ^ tm1) | (hf[j][3] ^ tm1);
          if (__all(bad == 0)) break;
          __builtin_amdgcn_s_sleep(1);
        }
#pragma unroll
        for (int kc = 0; kc < 16; ++kc) {
          union { i4v i; s8v s; } af;
          af.i[0] = hf[2 * kc][0];
          af.i[1] = hf[2 * kc][2];
          af.i[2] = hf[2 * kc + 1][0];
          af.i[3] = hf[2 * kc + 1][2];
          ah0 = __builtin_amdgcn_mfma_f32_16x16x32_bf16(af.s, wh0[kc], ah0, 0, 0, 0);
          ah1 = __builtin_amdgcn_mfma_f32_16x16x32_bf16(af.s, wh1[kc], ah1, 0, 0, 0);
        }
      }
      // ---- [2] zx(t) from LDS ring (x-waves run ahead; normally no wait) ----
      while (xcv < t + 1) {
        const int x0 = __hip_atomic_load(&xcnt[0], __ATOMIC_ACQUIRE,
                                         __HIP_MEMORY_SCOPE_WORKGROUP);
        const int x1 = __hip_atomic_load(&xcnt[1], __ATOMIC_ACQUIRE,
                                         __HIP_MEMORY_SCOPE_WORKGROUP);
        xcv = (x0 < x1) ? x0 : x1;
        if (xcv < t + 1) __builtin_amdgcn_s_sleep(1);
      }
      const f4v px0 = *(const f4v*)&zbuf[t & 3][uh][0][lane][0];
      const f4v px1 = *(const f4v*)&zbuf[t & 3][uh][1][lane][0];
      asm volatile("s_waitcnt lgkmcnt(0)" ::: "memory");
      __builtin_amdgcn_sched_barrier(0);
      __hip_atomic_store(&hcnt[uh], t + 1, __ATOMIC_RELEASE,
                         __HIP_MEMORY_SCOPE_WORKGROUP);  // slot t reusable
      // ---- [3] gates (lane pair n <-> n^8 packs {f,i} / {g,o}) ----
      float hv[4];
#pragma unroll
      for (int i = 0; i < 4; ++i) {
        const float s0 = ah0[i] + px0[i];
        const float s1 = ah1[i] + px1[i];
        const float p0 = __shfl_xor(s0, 8);
        const float p1 = __shfl_xor(s1, 8);
        const bool lo = (n < 8);
        const float zf = (lo ? s0 : p0) + bz0;
        const float zi = (lo ? p0 : s0) + bz1;
        const float zg = (lo ? s1 : p1) + bz2;
        const float zo = (lo ? p1 : s1) + bz3;
        const float fg = 1.f / (1.f + __expf(-zf));
        const float ig = 1.f / (1.f + __expf(-zi));
        const float gg = 1.f - 2.f / (__expf(2.f * zg) + 1.f);
        const float og = 1.f / (1.f + __expf(-zo));
        cst[i] = fg * cst[i] + ig * gg;
        hv[i] = og * (1.f - 2.f / (__expf(2.f * cst[i]) + 1.f));
      }
      // ---- [4] publish tagged h(t): fire-and-forget (tags ARE validity) ----
      float hn[4];
#pragma unroll
      for (int i = 0; i < 4; ++i) hn[i] = __shfl_down(hv[i], 1);
      if (n < 8 && !(n & 1)) {
        unsigned long long* hp =
            hbuf64 + (size_t)(t & 1) * BB * 256 + (us + n) / 2;
#pragma unroll
        for (int i = 0; i < 4; ++i) {
          const unsigned long long d =
              ((unsigned long long)(unsigned)t << 32) |
              (unsigned long long)cvtpk_bf16(hv[i], hn[i]);
          st_b64_cohere(hp + (size_t)(b0 + 4 * kg + i) * 256, d);
        }
      }
      // ---- [5] out stores (plain, drain lazily off critical path) ----
      if (n < 8) {
#pragma unroll
        for (int i = 0; i < 4; ++i)
          out[(size_t)t * BB * HH + (size_t)(b0 + 4 * kg + i) * HH + uu] = hv[i];
        if (t == TT - 1) {
#pragma unroll
          for (int i = 0; i < 4; ++i) {
            out[(size_t)TT * BB * HH + (size_t)(b0 + 4 * kg + i) * HH + uu] = hv[i];
            out[(size_t)TT * BB * HH + BB * HH +
                (size_t)(b0 + 4 * kg + i) * HH + uu] = cst[i];
          }
        }
      }
    }
  }
}

extern "C" void kernel_launch(void* const* d_in, const int* in_sizes, int n_in,
                              void* d_out, int out_size, void* d_ws,
                              size_t ws_size, hipStream_t stream) {
  const float* X   = (const float*)d_in[0];
  const float* Wf  = (const float*)d_in[1];
  const float* bfp = (const float*)d_in[2];
  const float* Wi  = (const float*)d_in[3];
  const float* bip = (const float*)d_in[4];
  const float* Wg  = (const float*)d_in[5];
  const float* bgp = (const float*)d_in[6];
  const float* Wo  = (const float*)d_in[7];
  const float* bop = (const float*)d_in[8];
  const float* ph  = (const float*)d_in[9];
  float* out = (float*)d_out;

  // ws: [0, 256KB) tagged-h double buffer {bf16 pair | u32 tag} u64 words
  unsigned long long* hbuf64 = (unsigned long long*)d_ws;

  qlstm_init<<<128, 256, 0, stream>>>(hbuf64);
  qlstm_main<<<NG * NS, NTHR, 0, stream>>>(X, Wf, bfp, Wi, bip, Wg, bgp, Wo,
                                           bop, ph, out, hbuf64);
}

// Round 8
// 5689.118 us; speedup vs baseline: 3.0599x; 1.4836x over previous
//
#include <hip/hip_runtime.h>

#define TT 1024
#define BB 64
#define DD 512
#define HH 512
#define NG 4       // batch groups (16 batches each)
#define BPG 16
#define NS 32      // hidden slices (16 units each)
#define NTHR 256

typedef short s8v __attribute__((ext_vector_type(8)));
typedef float f4v __attribute__((ext_vector_type(4)));
typedef int i4v __attribute__((ext_vector_type(4)));

static __device__ __forceinline__ unsigned short f2bf(float f) {
  union { float f; unsigned int u; } v; v.f = f;
  unsigned int r = v.u + 0x7FFFu + ((v.u >> 16) & 1u);  // RNE
  return (unsigned short)(r >> 16);
}
static __device__ __forceinline__ i4v ld_b128_cohere(const void* p) {
  i4v r;
  asm volatile("global_load_dwordx4 %0, %1, off sc0 sc1"
               : "=v"(r) : "v"(p) : "memory");
  return r;
}
static __device__ __forceinline__ int ld_b32_cohere(const void* p) {
  int r;
  asm volatile("global_load_dword %0, %1, off sc0 sc1\n\t"
               "s_waitcnt vmcnt(0)"
               : "=v"(r) : "v"(p) : "memory");
  return r;
}
static __device__ __forceinline__ void st_b32_cohere(void* p, unsigned int v) {
  asm volatile("global_store_dword %0, %1, off sc0 sc1"
               :: "v"(p), "v"(v) : "memory");
}
static __device__ __forceinline__ unsigned int cvtpk_bf16(float lo, float hi) {
  unsigned int r;
  asm("v_cvt_pk_bf16_f32 %0, %1, %2" : "=v"(r) : "v"(lo), "v"(hi));
  return r;
}

// Reset flags every launch (graph replays rerun this).
__global__ void __launch_bounds__(256, 1) qlstm_init(int* flags) {
  st_b32_cohere(flags + threadIdx.x, 0u);   // flags[NG][64] = 256 ints
}

__global__ void __launch_bounds__(NTHR, 1) qlstm_main(
    const float* __restrict__ X,
    const float* __restrict__ Wf, const float* __restrict__ bfp,
    const float* __restrict__ Wi, const float* __restrict__ bip,
    const float* __restrict__ Wg, const float* __restrict__ bgp,
    const float* __restrict__ Wo, const float* __restrict__ bop,
    const float* __restrict__ phase,
    float* __restrict__ out, int* __restrict__ flags,
    unsigned short* __restrict__ hbuf) {
  // 4-deep zx ring + progress counters (only LDS; no barriers in steady state)
  __shared__ float zbuf[4][2][2][64][4];  // [slot][uh][tile][lane][i]
  __shared__ int xcnt[2], hcnt[2];
  const int tid   = threadIdx.x;
  const int wv    = tid >> 6;
  const int lane  = tid & 63;
  const int n     = lane & 15;
  const int kg    = lane >> 4;
  const int group = blockIdx.x & (NG - 1);
  const int slice = blockIdx.x / NG;
  const int b0 = group * BPG;
  const int u0 = slice * 16;
  const bool isH = (wv >= 2);
  const int uh = wv & 1;               // unit half (8 units each)
  const int us = u0 + uh * 8;

  // Packed B-frag tiles: tile0 = {f(n<8)|i(n>=8)}, tile1 = {g|o}, unit us+(n&7)
  const float* Wt0 = (n < 8) ? Wf : Wi;
  const float* Wt1 = (n < 8) ? Wg : Wo;
  const int wcol = us + (n & 7);

  if (tid < 2) { xcnt[tid] = 0; hcnt[tid] = 0; }
  __syncthreads();   // the only barrier

  if (!isH) {
    // ========== x-waves: free-running zx producer (<=4 steps ahead) ==========
    s8v wx0[16], wx1[16];            // x-part weights (K rows 0..511)
#pragma unroll
    for (int kc = 0; kc < 16; ++kc)
#pragma unroll
      for (int j = 0; j < 8; ++j) {
        const int rx = kc * 32 + kg * 8 + j;
        wx0[kc][j] = (short)f2bf(Wt0[(size_t)rx * HH + wcol]);
        wx1[kc][j] = (short)f2bf(Wt1[(size_t)rx * HH + wcol]);
      }
    float4 xv[16];
    s8v xf[16];
    {  // preload x(0) frags
      const float4* Xr = (const float4*)(X + ((size_t)0 * BB + b0 + n) * DD) + kg * 2;
#pragma unroll
      for (int kc = 0; kc < 16; ++kc) {
        const float4 x1 = Xr[kc * 8];
        const float4 x2 = Xr[kc * 8 + 1];
        union { s8v s; unsigned int d[4]; } af;
        af.d[0] = cvtpk_bf16(x1.x, x1.y);
        af.d[1] = cvtpk_bf16(x1.z, x1.w);
        af.d[2] = cvtpk_bf16(x2.x, x2.y);
        af.d[3] = cvtpk_bf16(x2.z, x2.w);
        xf[kc] = af.s;
      }
    }
    int hcv = 0;
    for (int tx = 0; tx < TT; ++tx) {
      float4 yv[16];
      const bool pf = (tx + 1 < TT);
      if (pf) {  // issue next-step X loads early (latency hidden by MFMA+cvt)
        const float4* Xr =
            (const float4*)(X + ((size_t)(tx + 1) * BB + b0 + n) * DD) + kg * 2;
#pragma unroll
        for (int kc = 0; kc < 16; ++kc) { yv[kc] = Xr[kc * 8]; xv[kc] = Xr[kc * 8 + 1]; }
      }
      // ring throttle: slot tx&3 free once h consumed step tx-4
      while (tx >= hcv + 4) {
        const int h0 = __hip_atomic_load(&hcnt[0], __ATOMIC_ACQUIRE,
                                         __HIP_MEMORY_SCOPE_WORKGROUP);
        const int h1 = __hip_atomic_load(&hcnt[1], __ATOMIC_ACQUIRE,
                                         __HIP_MEMORY_SCOPE_WORKGROUP);
        hcv = (h0 < h1) ? h0 : h1;
        if (tx >= hcv + 4) __builtin_amdgcn_s_sleep(1);
      }
      f4v a0 = {0.f, 0.f, 0.f, 0.f}, a1 = {0.f, 0.f, 0.f, 0.f};
#pragma unroll
      for (int kc = 0; kc < 16; ++kc) {
        a0 = __builtin_amdgcn_mfma_f32_16x16x32_bf16(xf[kc], wx0[kc], a0, 0, 0, 0);
        a1 = __builtin_amdgcn_mfma_f32_16x16x32_bf16(xf[kc], wx1[kc], a1, 0, 0, 0);
      }
      *(f4v*)&zbuf[tx & 3][uh][0][lane][0] = a0;
      *(f4v*)&zbuf[tx & 3][uh][1][lane][0] = a1;
      asm volatile("s_waitcnt lgkmcnt(0)" ::: "memory");
      __hip_atomic_store(&xcnt[uh], tx + 1, __ATOMIC_RELEASE,
                         __HIP_MEMORY_SCOPE_WORKGROUP);
      if (pf) {
#pragma unroll
        for (int kc = 0; kc < 16; ++kc) {
          union { s8v s; unsigned int d[4]; } af;
          af.d[0] = cvtpk_bf16(yv[kc].x, yv[kc].y);
          af.d[1] = cvtpk_bf16(yv[kc].z, yv[kc].w);
          af.d[2] = cvtpk_bf16(xv[kc].x, xv[kc].y);
          af.d[3] = cvtpk_bf16(xv[kc].z, xv[kc].w);
          xf[kc] = af.s;
        }
      }
    }
  } else {
    // ================= h-waves: the critical path =================
    s8v wh0[16], wh1[16];            // h-part weights (K rows 512..1023)
#pragma unroll
    for (int kc = 0; kc < 16; ++kc)
#pragma unroll
      for (int j = 0; j < 8; ++j) {
        const int rh = 512 + kc * 32 + kg * 8 + j;
        wh0[kc][j] = (short)f2bf(Wt0[(size_t)rh * HH + wcol]);
        wh1[kc][j] = (short)f2bf(Wt1[(size_t)rh * HH + wcol]);
      }
    const int uu = us + (n & 7);
    const float bz0 = bfp[uu] + phase[uu];
    const float bz1 = bip[uu] + phase[uu];
    const float bz2 = bgp[uu] + phase[uu];
    const float bz3 = bop[uu] + phase[uu];
    float cst[4] = {0.f, 0.f, 0.f, 0.f};
    int xcv = 0;
    // per-WAVE flag: index = slice*2 + uh within the group's 64
    int* myflag = flags + group * 64 + slice * 2 + uh;
    const int* pollp = flags + group * 64 + lane;

    for (int t = 0; t < TT; ++t) {
      // ---- [1] zx(t) from ring (x-waves run ahead; rarely waits) ----
      while (xcv < t + 1) {
        const int x0 = __hip_atomic_load(&xcnt[0], __ATOMIC_ACQUIRE,
                                         __HIP_MEMORY_SCOPE_WORKGROUP);
        const int x1 = __hip_atomic_load(&xcnt[1], __ATOMIC_ACQUIRE,
                                         __HIP_MEMORY_SCOPE_WORKGROUP);
        xcv = (x0 < x1) ? x0 : x1;
        if (xcv < t + 1) __builtin_amdgcn_s_sleep(1);
      }
      const f4v px0 = *(const f4v*)&zbuf[t & 3][uh][0][lane][0];
      const f4v px1 = *(const f4v*)&zbuf[t & 3][uh][1][lane][0];
      asm volatile("s_waitcnt lgkmcnt(0)" ::: "memory");
      __hip_atomic_store(&hcnt[uh], t + 1, __ATOMIC_RELEASE,
                         __HIP_MEMORY_SCOPE_WORKGROUP);  // slot t reusable
      // ---- [2] flag poll (4B/lane granularity) then ONE h load ----
      f4v ah0 = {0.f, 0.f, 0.f, 0.f}, ah1 = {0.f, 0.f, 0.f, 0.f};
      if (t > 0) {
        for (;;) {
          const int v = ld_b32_cohere(pollp);
          if (__all(v >= t)) break;
          __builtin_amdgcn_s_sleep(1);
        }
        // h(t-1) directly in A-frag layout: lane (row=b0+n, k=kg*8+kc*32+j)
        const unsigned short* hb = hbuf + (size_t)((t - 1) & 1) * BB * HH +
                                   (size_t)(b0 + n) * HH + kg * 8;
        i4v hf[16];
#pragma unroll
        for (int kc = 0; kc < 16; ++kc) hf[kc] = ld_b128_cohere(hb + kc * 32);
        asm volatile("s_waitcnt vmcnt(0)" ::: "memory");
        __builtin_amdgcn_sched_barrier(0);
#pragma unroll
        for (int kc = 0; kc < 16; ++kc) {
          union { i4v i; s8v s; } af; af.i = hf[kc];
          ah0 = __builtin_amdgcn_mfma_f32_16x16x32_bf16(af.s, wh0[kc], ah0, 0, 0, 0);
          ah1 = __builtin_amdgcn_mfma_f32_16x16x32_bf16(af.s, wh1[kc], ah1, 0, 0, 0);
        }
      }
      // ---- [3] gates in-register (lane pair n <-> n^8 packs {f,i}/{g,o}) ----
      float hv[4];
#pragma unroll
      for (int i = 0; i < 4; ++i) {
        const float s0 = ah0[i] + px0[i];
        const float s1 = ah1[i] + px1[i];
        const float p0 = __shfl_xor(s0, 8);
        const float p1 = __shfl_xor(s1, 8);
        const bool lo = (n < 8);
        const float zf = (lo ? s0 : p0) + bz0;
        const float zi = (lo ? p0 : s0) + bz1;
        const float zg = (lo ? s1 : p1) + bz2;
        const float zo = (lo ? p1 : s1) + bz3;
        const float fg = 1.f / (1.f + __expf(-zf));
        const float ig = 1.f / (1.f + __expf(-zi));
        const float gg = 1.f - 2.f / (__expf(2.f * zg) + 1.f);
        const float og = 1.f / (1.f + __expf(-zo));
        cst[i] = fg * cst[i] + ig * gg;
        hv[i] = og * (1.f - 2.f / (__expf(2.f * cst[i]) + 1.f));
      }
      // ---- [4] publish h (bf16 pairs), drain h-stores ONLY, then flag ----
      float hn[4];
#pragma unroll
      for (int i = 0; i < 4; ++i) hn[i] = __shfl_down(hv[i], 1);
      if (n < 8 && !(n & 1)) {
        unsigned short* hp = hbuf + (size_t)(t & 1) * BB * HH + (us + n);
#pragma unroll
        for (int i = 0; i < 4; ++i)
          st_b32_cohere(hp + (size_t)(b0 + 4 * kg + i) * HH,
                        cvtpk_bf16(hv[i], hn[i]));
      }
      asm volatile("s_waitcnt vmcnt(0)" ::: "memory");
      if (lane == 0) st_b32_cohere(myflag, (unsigned int)(t + 1));
      // ---- [5] out stores LAST (latency absorbed by next step's poll) ----
      if (n < 8) {
#pragma unroll
        for (int i = 0; i < 4; ++i)
          out[(size_t)t * BB * HH + (size_t)(b0 + 4 * kg + i) * HH + uu] = hv[i];
        if (t == TT - 1) {
#pragma unroll
          for (int i = 0; i < 4; ++i) {
            out[(size_t)TT * BB * HH + (size_t)(b0 + 4 * kg + i) * HH + uu] = hv[i];
            out[(size_t)TT * BB * HH + BB * HH +
                (size_t)(b0 + 4 * kg + i) * HH + uu] = cst[i];
          }
        }
      }
    }
  }
}

extern "C" void kernel_launch(void* const* d_in, const int* in_sizes, int n_in,
                              void* d_out, int out_size, void* d_ws,
                              size_t ws_size, hipStream_t stream) {
  const float* X   = (const float*)d_in[0];
  const float* Wf  = (const float*)d_in[1];
  const float* bfp = (const float*)d_in[2];
  const float* Wi  = (const float*)d_in[3];
  const float* bip = (const float*)d_in[4];
  const float* Wg  = (const float*)d_in[5];
  const float* bgp = (const float*)d_in[6];
  const float* Wo  = (const float*)d_in[7];
  const float* bop = (const float*)d_in[8];
  const float* ph  = (const float*)d_in[9];
  float* out = (float*)d_out;

  // ws: [0,1KB) flags[NG][64]; [4KB, 4KB+128KB) bf16 h double-buffer
  int* flags = (int*)d_ws;
  unsigned short* hbuf = (unsigned short*)((char*)d_ws + 4096);

  qlstm_init<<<1, 256, 0, stream>>>(flags);
  qlstm_main<<<NG * NS, NTHR, 0, stream>>>(X, Wf, bfp, Wi, bip, Wg, bgp, Wo,
                                           bop, ph, out, flags, hbuf);
}

// Round 9
// 3120.954 us; speedup vs baseline: 5.5778x; 1.8229x over previous
//
#include <hip/hip_runtime.h>

#define TT 1024
#define BB 64
#define DD 512
#define HH 512
#define NG 4       // batch groups (16 batches each)
#define BPG 16
#define NS 32      // hidden slices (16 units each)
#define NTHR 256

typedef short s8v __attribute__((ext_vector_type(8)));
typedef float f4v __attribute__((ext_vector_type(4)));
typedef int i4v __attribute__((ext_vector_type(4)));

static __device__ __forceinline__ unsigned short f2bf(float f) {
  union { float f; unsigned int u; } v; v.f = f;
  unsigned int r = v.u + 0x7FFFu + ((v.u >> 16) & 1u);  // RNE
  return (unsigned short)(r >> 16);
}
static __device__ __forceinline__ i4v ld_b128_cohere(const void* p) {
  i4v r;
  asm volatile("global_load_dwordx4 %0, %1, off sc0 sc1"
               : "=v"(r) : "v"(p) : "memory");
  return r;
}
static __device__ __forceinline__ int ld_b32_cohere(const void* p) {
  int r;
  asm volatile("global_load_dword %0, %1, off sc0 sc1\n\t"
               "s_waitcnt vmcnt(0)"
               : "=v"(r) : "v"(p) : "memory");
  return r;
}
static __device__ __forceinline__ void st_b32_cohere(void* p, unsigned int v) {
  asm volatile("global_store_dword %0, %1, off sc0 sc1"
               :: "v"(p), "v"(v) : "memory");
}
static __device__ __forceinline__ unsigned int cvtpk_bf16(float lo, float hi) {
  unsigned int r;
  asm("v_cvt_pk_bf16_f32 %0, %1, %2" : "=v"(r) : "v"(lo), "v"(hi));
  return r;
}

// Reset flags every launch (graph replays rerun this).
__global__ void __launch_bounds__(128, 1) qlstm_init(int* flags) {
  st_b32_cohere(flags + threadIdx.x, 0u);   // flags[NG][NS] = 128 ints
}

__global__ void __launch_bounds__(NTHR, 1) qlstm_main(
    const float* __restrict__ X,
    const float* __restrict__ Wf, const float* __restrict__ bfp,
    const float* __restrict__ Wi, const float* __restrict__ bip,
    const float* __restrict__ Wg, const float* __restrict__ bgp,
    const float* __restrict__ Wo, const float* __restrict__ bop,
    const float* __restrict__ phase,
    float* __restrict__ out, int* __restrict__ flags,
    unsigned short* __restrict__ hbuf) {
  // z-partials: zx (parity-double-buffered: written 1 step ahead), zh (same
  // step, fenced by the two barriers). 40 KB total.
  __shared__ float zx[2][2][4][64][4];  // [par][khalf][tile][lane][i]
  __shared__ float zh[2][4][64][4];     // [khalf][tile][lane][i]
  const int tid   = threadIdx.x;
  const int wv    = tid >> 6;
  const int lane  = tid & 63;
  const int n     = lane & 15;
  const int kg    = lane >> 4;
  const int group = blockIdx.x & (NG - 1);
  const int slice = blockIdx.x >> 2;
  const int b0 = group * BPG;
  const int u0 = slice * 16;
  const bool isH = (wv >= 2);
  const int kh = wv & 1;               // K-half within role (x: 0..511, h: 512..1023)

  // Per-wave weights: 4 tiles x K=256. Tile T: unit-half T>>1, gates
  // {f,i} (T even) / {g,o} (T odd); col n<8 -> first gate, n>=8 -> second.
  const int wcol = u0 + (n & 7);
  s8v wreg[4][8];
#pragma unroll
  for (int T = 0; T < 4; ++T) {
    const float* Wsel = (T & 1) ? ((n < 8) ? Wg : Wo) : ((n < 8) ? Wf : Wi);
    const float* Wp = Wsel + (size_t)((isH ? 512 : 0) + kh * 256 + kg * 8) * HH
                    + wcol + (T >> 1) * 8;
#pragma unroll
    for (int kc = 0; kc < 8; ++kc)
#pragma unroll
      for (int j = 0; j < 8; ++j)
        wreg[T][kc][j] = (short)f2bf(Wp[(size_t)(kc * 32 + j) * HH]);
  }

  // gate-phase constants: thread owns (batch gb, unit gu)
  const int gb = tid >> 4, gu = tid & 15;
  const int uu = u0 + gu;
  const float bzf = bfp[uu] + phase[uu];
  const float bzi = bip[uu] + phase[uu];
  const float bzg = bgp[uu] + phase[uu];
  const float bzo = bop[uu] + phase[uu];
  float cst = 0.f;

  // prologue: zero zh (h(-1)=0), x-waves compute zx(0) and issue LD(1)
  for (int p = tid; p < 2 * 4 * 64 * 4; p += NTHR) ((float*)zh)[p] = 0.f;
  float4 xv[16];
  s8v xf[8];
  if (!isH) {
    const float* Xr = X + ((size_t)0 * BB + b0 + n) * DD + kh * 256 + kg * 8;
#pragma unroll
    for (int kc = 0; kc < 8; ++kc) {
      xv[2 * kc]     = *(const float4*)(Xr + kc * 32);
      xv[2 * kc + 1] = *(const float4*)(Xr + kc * 32 + 4);
    }
#pragma unroll
    for (int kc = 0; kc < 8; ++kc) {
      union { s8v s; unsigned int d[4]; } af;
      af.d[0] = cvtpk_bf16(xv[2 * kc].x, xv[2 * kc].y);
      af.d[1] = cvtpk_bf16(xv[2 * kc].z, xv[2 * kc].w);
      af.d[2] = cvtpk_bf16(xv[2 * kc + 1].x, xv[2 * kc + 1].y);
      af.d[3] = cvtpk_bf16(xv[2 * kc + 1].z, xv[2 * kc + 1].w);
      xf[kc] = af.s;
    }
    f4v acc[4] = {{0.f,0.f,0.f,0.f},{0.f,0.f,0.f,0.f},{0.f,0.f,0.f,0.f},{0.f,0.f,0.f,0.f}};
#pragma unroll
    for (int kc = 0; kc < 8; ++kc)
#pragma unroll
      for (int T = 0; T < 4; ++T)
        acc[T] = __builtin_amdgcn_mfma_f32_16x16x32_bf16(xf[kc], wreg[T][kc], acc[T], 0, 0, 0);
#pragma unroll
    for (int T = 0; T < 4; ++T) *(f4v*)&zx[0][kh][T][lane][0] = acc[T];
    const float* X1 = X + ((size_t)1 * BB + b0 + n) * DD + kh * 256 + kg * 8;
#pragma unroll
    for (int kc = 0; kc < 8; ++kc) {
      xv[2 * kc]     = *(const float4*)(X1 + kc * 32);
      xv[2 * kc + 1] = *(const float4*)(X1 + kc * 32 + 4);
    }
  }

  int* myflag = flags + group * NS + slice;
  const int* pollp = flags + group * NS + (lane & 31);

  for (int t = 0; t < TT; ++t) {
    // ---------- P1: x-waves build zx(t+1); h-waves poll+load+MFMA zh(t) ----
    if (!isH) {
      if (t + 1 < TT) {
        // cvt LD(t+1) (issued one phase ago -> latency long hidden)
#pragma unroll
        for (int kc = 0; kc < 8; ++kc) {
          union { s8v s; unsigned int d[4]; } af;
          af.d[0] = cvtpk_bf16(xv[2 * kc].x, xv[2 * kc].y);
          af.d[1] = cvtpk_bf16(xv[2 * kc].z, xv[2 * kc].w);
          af.d[2] = cvtpk_bf16(xv[2 * kc + 1].x, xv[2 * kc + 1].y);
          af.d[3] = cvtpk_bf16(xv[2 * kc + 1].z, xv[2 * kc + 1].w);
          xf[kc] = af.s;
        }
        f4v acc[4] = {{0.f,0.f,0.f,0.f},{0.f,0.f,0.f,0.f},{0.f,0.f,0.f,0.f},{0.f,0.f,0.f,0.f}};
#pragma unroll
        for (int kc = 0; kc < 8; ++kc)
#pragma unroll
          for (int T = 0; T < 4; ++T)
            acc[T] = __builtin_amdgcn_mfma_f32_16x16x32_bf16(xf[kc], wreg[T][kc], acc[T], 0, 0, 0);
#pragma unroll
        for (int T = 0; T < 4; ++T)
          *(f4v*)&zx[(t + 1) & 1][kh][T][lane][0] = acc[T];
      }
    } else if (t > 0) {
      for (;;) {
        const int v = ld_b32_cohere(pollp);
        if (__all(v >= t)) break;
        __builtin_amdgcn_s_sleep(1);
      }
      // h(t-1) direct global->A-frag: lane (row=b0+n, k=kh*256+kc*32+kg*8+j)
      const unsigned short* hb = hbuf + (size_t)((t - 1) & 1) * BB * HH +
                                 (size_t)(b0 + n) * HH + kh * 256 + kg * 8;
      i4v hf[8];
#pragma unroll
      for (int kc = 0; kc < 8; ++kc) hf[kc] = ld_b128_cohere(hb + kc * 32);
      asm volatile("s_waitcnt vmcnt(0)" ::: "memory");   // rule-18 fence
      __builtin_amdgcn_sched_barrier(0);
      f4v acc[4] = {{0.f,0.f,0.f,0.f},{0.f,0.f,0.f,0.f},{0.f,0.f,0.f,0.f},{0.f,0.f,0.f,0.f}};
#pragma unroll
      for (int kc = 0; kc < 8; ++kc) {
        union { i4v i; s8v s; } af; af.i = hf[kc];
#pragma unroll
        for (int T = 0; T < 4; ++T)
          acc[T] = __builtin_amdgcn_mfma_f32_16x16x32_bf16(af.s, wreg[T][kc], acc[T], 0, 0, 0);
      }
#pragma unroll
      for (int T = 0; T < 4; ++T) *(f4v*)&zh[kh][T][lane][0] = acc[T];
    }
    __syncthreads();                                    // bar1

    // ---------- P3: gates on ALL 256 threads (1 unit each, no shuffles) ----
    const int par = t & 1;
    const int Lf  = (gb >> 2) * 16 + (gu & 7);
    const int T0  = (gu >> 3) * 2;
    const int ci  = gb & 3;
    const float zfv = zx[par][0][T0][Lf][ci]     + zx[par][1][T0][Lf][ci]
                    + zh[0][T0][Lf][ci]          + zh[1][T0][Lf][ci] + bzf;
    const float ziv = zx[par][0][T0][Lf+8][ci]   + zx[par][1][T0][Lf+8][ci]
                    + zh[0][T0][Lf+8][ci]        + zh[1][T0][Lf+8][ci] + bzi;
    const float zgv = zx[par][0][T0+1][Lf][ci]   + zx[par][1][T0+1][Lf][ci]
                    + zh[0][T0+1][Lf][ci]        + zh[1][T0+1][Lf][ci] + bzg;
    const float zov = zx[par][0][T0+1][Lf+8][ci] + zx[par][1][T0+1][Lf+8][ci]
                    + zh[0][T0+1][Lf+8][ci]      + zh[1][T0+1][Lf+8][ci] + bzo;
    const float fg = 1.f / (1.f + __expf(-zfv));
    const float ig = 1.f / (1.f + __expf(-ziv));
    const float gg = 1.f - 2.f / (__expf(2.f * zgv) + 1.f);
    const float og = 1.f / (1.f + __expf(-zov));
    cst = fg * cst + ig * gg;
    const float hv = og * (1.f - 2.f / (__expf(2.f * cst) + 1.f));

    // publish h (bf16 pair per even thread), drain h-stores only
    const float hn = __shfl_down(hv, 1);
    if (!(gu & 1))
      st_b32_cohere(hbuf + (size_t)par * BB * HH + (size_t)(b0 + gb) * HH + uu,
                    cvtpk_bf16(hv, hn));
    asm volatile("s_waitcnt vmcnt(0)" ::: "memory");
    // x-waves: issue LD(t+2) AFTER the drain (consumed next step's P1)
    if (!isH && t + 2 < TT) {
      const float* Xr = X + ((size_t)(t + 2) * BB + b0 + n) * DD + kh * 256 + kg * 8;
#pragma unroll
      for (int kc = 0; kc < 8; ++kc) {
        xv[2 * kc]     = *(const float4*)(Xr + kc * 32);
        xv[2 * kc + 1] = *(const float4*)(Xr + kc * 32 + 4);
      }
    }
    __syncthreads();                                    // bar2
    if (tid == 0) st_b32_cohere(myflag, (unsigned int)(t + 1));

    // ---------- P4: out stores after the flag (off critical path) ----------
    out[(size_t)t * BB * HH + (size_t)(b0 + gb) * HH + uu] = hv;
    if (t == TT - 1) {
      out[(size_t)TT * BB * HH + (size_t)(b0 + gb) * HH + uu] = hv;          // hx
      out[(size_t)TT * BB * HH + BB * HH + (size_t)(b0 + gb) * HH + uu] = cst; // cx
    }
  }
}

extern "C" void kernel_launch(void* const* d_in, const int* in_sizes, int n_in,
                              void* d_out, int out_size, void* d_ws,
                              size_t ws_size, hipStream_t stream) {
  const float* X   = (const float*)d_in[0];
  const float* Wf  = (const float*)d_in[1];
  const float* bfp = (const float*)d_in[2];
  const float* Wi  = (const float*)d_in[3];
  const float* bip = (const float*)d_in[4];
  const float* Wg  = (const float*)d_in[5];
  const float* bgp = (const float*)d_in[6];
  const float* Wo  = (const float*)d_in[7];
  const float* bop = (const float*)d_in[8];
  const float* ph  = (const float*)d_in[9];
  float* out = (float*)d_out;

  // ws: [0, 512B) flags[NG][NS]; [4KB, 4KB+128KB) bf16 h double-buffer
  int* flags = (int*)d_ws;
  unsigned short* hbuf = (unsigned short*)((char*)d_ws + 4096);

  qlstm_init<<<1, 128, 0, stream>>>(flags);
  qlstm_main<<<NG * NS, NTHR, 0, stream>>>(X, Wf, bfp, Wi, bip, Wg, bgp, Wo,
                                           bop, ph, out, flags, hbuf);
}